// Round 2
// baseline (1025.067 us; speedup 1.0000x reference)
//
#include <hip/hip_runtime.h>
#include <hip/hip_bf16.h>

typedef float f32x4 __attribute__((ext_vector_type(4)));
typedef short s16x8 __attribute__((ext_vector_type(8)));

__device__ __forceinline__ short f2bf(float f) {
    union { float f; unsigned int u; } c; c.f = f;
    unsigned int u = c.u;
    u += 0x7FFFu + ((u >> 16) & 1u);          // round-to-nearest-even
    return (short)(u >> 16);
}
__device__ __forceinline__ float bf2f(unsigned int v16) {   // v16 holds bf16 in low 16 bits
    union { unsigned int u; float f; } c; c.u = v16 << 16; return c.f;
}
__device__ __forceinline__ s16x8 cvt8(float4 f0, float4 f1) {
    s16x8 v;
    v[0] = f2bf(f0.x); v[1] = f2bf(f0.y); v[2] = f2bf(f0.z); v[3] = f2bf(f0.w);
    v[4] = f2bf(f1.x); v[5] = f2bf(f1.y); v[6] = f2bf(f1.z); v[7] = f2bf(f1.w);
    return v;
}

// ---------------- weight packing: MFMA B-fragment order ----------------
// out[((ks*nbTot + nb)*64 + lane)*8 + j] = bf16( W[(ks*32 + (lane>>4)*8 + j)][nb*16 + (lane&15)] )
__global__ void pack_w(const float* __restrict__ W, short* __restrict__ out,
                       int Kreal, int N, int nbTot, int total) {
    int tid = blockIdx.x * 256 + threadIdx.x;
    if (tid >= total) return;
    int j  = tid & 7;
    int l  = (tid >> 3) & 63;
    int blk = tid >> 9;            // ks*nbTot + nb
    int nb = blk % nbTot, ks = blk / nbTot;
    int k = ks * 32 + (l >> 4) * 8 + j;
    int n = nb * 16 + (l & 15);
    out[tid] = (k < Kreal) ? f2bf(W[(long)k * N + n]) : (short)0;
}

// ---------------- wave-local layernorm over 256 cols ----------------
// acc C-layout: lane(r,kg) holds rows kg*4+j (j=0..3), col ni*16+r.
// Row lives entirely within one 16-lane group -> 4-step shfl_xor reduce.
__device__ __forceinline__ void ln_wave(f32x4 (&acc)[16], const float* __restrict__ g,
                                        const float* __restrict__ bl, int r) {
#pragma unroll
    for (int j = 0; j < 4; ++j) {
        float s = 0.f, q = 0.f;
#pragma unroll
        for (int ni = 0; ni < 16; ++ni) { float v = acc[ni][j]; s += v; q += v * v; }
#pragma unroll
        for (int m = 1; m < 16; m <<= 1) { s += __shfl_xor(s, m, 64); q += __shfl_xor(q, m, 64); }
        float mean = s * (1.f / 256.f);
        float var  = fmaxf(q * (1.f / 256.f) - mean * mean, 0.f);
        float rstd = rsqrtf(var + 1e-5f);
#pragma unroll
        for (int ni = 0; ni < 16; ++ni) acc[ni][j] = (acc[ni][j] - mean) * rstd;
    }
#pragma unroll
    for (int ni = 0; ni < 16; ++ni) {
        float gg = g[ni * 16 + r], bb = bl[ni * 16 + r];
#pragma unroll
        for (int j = 0; j < 4; ++j) acc[ni][j] = acc[ni][j] * gg + bb;
    }
}

// ---------------- main fused kernel: 1 wave per block, 16 rows per wave ----------------
__global__ __launch_bounds__(64, 3) void deq_main(
    const float* __restrict__ x, const float* __restrict__ z,
    const float* __restrict__ b_inp, const float* __restrict__ g_lni, const float* __restrict__ b_lni,
    const float* __restrict__ b1, const float* __restrict__ g_ln1, const float* __restrict__ b_ln1,
    const float* __restrict__ b2, const float* __restrict__ g_ln2, const float* __restrict__ b_ln2,
    const float* __restrict__ g_ln3, const float* __restrict__ b_ln3,
    const float* __restrict__ b_out,
    const s16x8* __restrict__ Wp1, const s16x8* __restrict__ Wp2,
    const s16x8* __restrict__ WpI, const s16x8* __restrict__ WpO,
    float* __restrict__ out_dx, float* __restrict__ out_z)
{
    __shared__ __align__(16) short T_sh[16 * 256];   // 8KB wave-local transpose buffer (z1, then z_out)

    const int lane = threadIdx.x & 63;
    const int r = lane & 15, kg = lane >> 4;
    const long r0 = (long)blockIdx.x * 16;
    const int swzr = (r & 7) << 4;                   // A-frag read swizzle (row = r)

    f32x4 acc[16];
#pragma unroll
    for (int ni = 0; ni < 16; ++ni) acc[ni] = (f32x4){0.f, 0.f, 0.f, 0.f};

    // ---- GEMM1: z @ W1, A-frags straight from global (each z element read once) ----
    const float* zrow = z + (r0 + r) * 256 + kg * 8;
#pragma unroll
    for (int ks = 0; ks < 8; ++ks) {
        const float4* zp = (const float4*)(zrow + ks * 32);
        s16x8 a = cvt8(zp[0], zp[1]);
#pragma unroll
        for (int ni = 0; ni < 16; ++ni)
            acc[ni] = __builtin_amdgcn_mfma_f32_16x16x32_bf16(a, Wp1[(ks * 16 + ni) * 64 + lane], acc[ni], 0, 0, 0);
    }
    // +b1, relu, LN1 -> z1
#pragma unroll
    for (int ni = 0; ni < 16; ++ni) {
        float bb = b1[ni * 16 + r];
#pragma unroll
        for (int j = 0; j < 4; ++j) acc[ni][j] = fmaxf(acc[ni][j] + bb, 0.f);
    }
    ln_wave(acc, g_ln1, b_ln1, r);

    // ---- keep z1 as packed bf16 in regs; write bf16 copy to LDS for GEMM2 A-frags ----
    unsigned z1p[32];
#pragma unroll
    for (int ni = 0; ni < 16; ++ni) {
        unsigned b0 = (unsigned short)f2bf(acc[ni][0]);
        unsigned b1_ = (unsigned short)f2bf(acc[ni][1]);
        unsigned b2_ = (unsigned short)f2bf(acc[ni][2]);
        unsigned b3 = (unsigned short)f2bf(acc[ni][3]);
        z1p[ni * 2]     = b0 | (b1_ << 16);
        z1p[ni * 2 + 1] = b2_ | (b3 << 16);
    }
#pragma unroll
    for (int ni = 0; ni < 16; ++ni)
#pragma unroll
        for (int j = 0; j < 4; ++j) {
            int row = kg * 4 + j;
            short v = (short)(z1p[ni * 2 + (j >> 1)] >> ((j & 1) * 16));
            *(short*)((char*)T_sh + ((row * 512 + (ni * 16 + r) * 2) ^ ((row & 7) << 4))) = v;
        }

    // ---- x-GEMM -> xinp (reuse acc; overlaps with z1 LDS writes draining) ----
#pragma unroll
    for (int ni = 0; ni < 16; ++ni) acc[ni] = (f32x4){0.f, 0.f, 0.f, 0.f};
    {
        const float* xrow = x + (r0 + r) * 48;
        const float4* xp0 = (const float4*)(xrow + kg * 8);
        s16x8 a0 = cvt8(xp0[0], xp0[1]);
        s16x8 a1 = (s16x8){0, 0, 0, 0, 0, 0, 0, 0};
        if (kg < 2) {
            const float4* xp1 = (const float4*)(xrow + 32 + kg * 8);
            a1 = cvt8(xp1[0], xp1[1]);
        }
#pragma unroll
        for (int ni = 0; ni < 16; ++ni)
            acc[ni] = __builtin_amdgcn_mfma_f32_16x16x32_bf16(a0, WpI[ni * 64 + lane], acc[ni], 0, 0, 0);
#pragma unroll
        for (int ni = 0; ni < 16; ++ni)
            acc[ni] = __builtin_amdgcn_mfma_f32_16x16x32_bf16(a1, WpI[(16 + ni) * 64 + lane], acc[ni], 0, 0, 0);
    }
#pragma unroll
    for (int ni = 0; ni < 16; ++ni) {
        float bb = b_inp[ni * 16 + r];
#pragma unroll
        for (int j = 0; j < 4; ++j) acc[ni][j] += bb;
    }
    ln_wave(acc, g_lni, b_lni, r);        // acc = xinp
#pragma unroll
    for (int ni = 0; ni < 16; ++ni) {     // + b2 : C-init for GEMM2
        float bb = b2[ni * 16 + r];
#pragma unroll
        for (int j = 0; j < 4; ++j) acc[ni][j] += bb;
    }

    // ---- GEMM2: inner_pre = xinp + b2 + z1 @ W2 (A-frags from LDS) ----
#pragma unroll
    for (int ks = 0; ks < 8; ++ks) {
        s16x8 a = *(const s16x8*)((const char*)T_sh + ((r * 512 + (ks * 32 + kg * 8) * 2) ^ swzr));
#pragma unroll
        for (int ni = 0; ni < 16; ++ni)
            acc[ni] = __builtin_amdgcn_mfma_f32_16x16x32_bf16(a, Wp2[(ks * 16 + ni) * 64 + lane], acc[ni], 0, 0, 0);
    }
    ln_wave(acc, g_ln2, b_ln2, r);        // acc = inner

    // ---- z_out = LN3(relu(z1 + inner)) ----
#pragma unroll
    for (int ni = 0; ni < 16; ++ni)
#pragma unroll
        for (int j = 0; j < 4; ++j) {
            unsigned u = z1p[ni * 2 + (j >> 1)];
            float z1v = bf2f((j & 1) ? (u >> 16) : (u & 0xffffu));
            acc[ni][j] = fmaxf(acc[ni][j] + z1v, 0.f);
        }
    ln_wave(acc, g_ln3, b_ln3, r);        // acc = z_out

    // ---- store z_out (f32) + bf16 copy to LDS for the output GEMM ----
#pragma unroll
    for (int ni = 0; ni < 16; ++ni)
#pragma unroll
        for (int j = 0; j < 4; ++j) {
            int row = kg * 4 + j;
            float v = acc[ni][j];
            out_z[(r0 + row) * 256 + ni * 16 + r] = v;
            *(short*)((char*)T_sh + ((row * 512 + (ni * 16 + r) * 2) ^ ((row & 7) << 4))) = f2bf(v);
        }

    // ---- dx = z_out @ W_out + b_out ----
    f32x4 ao[2];
    ao[0] = (f32x4){0.f, 0.f, 0.f, 0.f};
    ao[1] = (f32x4){0.f, 0.f, 0.f, 0.f};
#pragma unroll
    for (int ks = 0; ks < 8; ++ks) {
        s16x8 a = *(const s16x8*)((const char*)T_sh + ((r * 512 + (ks * 32 + kg * 8) * 2) ^ swzr));
#pragma unroll
        for (int ni = 0; ni < 2; ++ni)
            ao[ni] = __builtin_amdgcn_mfma_f32_16x16x32_bf16(a, WpO[(ks * 2 + ni) * 64 + lane], ao[ni], 0, 0, 0);
    }
#pragma unroll
    for (int ni = 0; ni < 2; ++ni) {
        float bb = b_out[ni * 16 + r];
#pragma unroll
        for (int j = 0; j < 4; ++j)
            out_dx[(r0 + kg * 4 + j) * 32 + ni * 16 + r] = ao[ni][j] + bb;
    }
}

extern "C" void kernel_launch(void* const* d_in, const int* in_sizes, int n_in,
                              void* d_out, int out_size, void* d_ws, size_t ws_size,
                              hipStream_t stream) {
    const float* x      = (const float*)d_in[0];
    const float* z      = (const float*)d_in[1];
    const float* W_inp  = (const float*)d_in[2];
    const float* b_inp  = (const float*)d_in[3];
    const float* g_lni  = (const float*)d_in[4];
    const float* b_lni  = (const float*)d_in[5];
    const float* W1     = (const float*)d_in[6];
    const float* b1     = (const float*)d_in[7];
    const float* g_ln1  = (const float*)d_in[8];
    const float* b_ln1  = (const float*)d_in[9];
    const float* W2     = (const float*)d_in[10];
    const float* b2     = (const float*)d_in[11];
    const float* g_ln2  = (const float*)d_in[12];
    const float* b_ln2  = (const float*)d_in[13];
    const float* g_ln3  = (const float*)d_in[14];
    const float* b_ln3  = (const float*)d_in[15];
    const float* W_out  = (const float*)d_in[16];
    const float* b_out  = (const float*)d_in[17];

    short* Wp1 = (short*)d_ws;            // 8*16*64*8  = 65536 bf16
    short* Wp2 = Wp1 + 65536;             // 65536
    short* WpI = Wp2 + 65536;             // 2*16*64*8  = 16384
    short* WpO = WpI + 16384;             // 8*2*64*8   = 8192

    pack_w<<<256, 256, 0, stream>>>(W1,    Wp1, 256, 256, 16, 65536);
    pack_w<<<256, 256, 0, stream>>>(W2,    Wp2, 256, 256, 16, 65536);
    pack_w<<< 64, 256, 0, stream>>>(W_inp, WpI,  48, 256, 16, 16384);
    pack_w<<< 32, 256, 0, stream>>>(W_out, WpO, 256,  32,  2,  8192);

    const long B = 262144;
    float* out_dx = (float*)d_out;
    float* out_z  = out_dx + B * 32;
    deq_main<<<B / 16, 64, 0, stream>>>(x, z, b_inp, g_lni, b_lni,
                                        b1, g_ln1, b_ln1, b2, g_ln2, b_ln2,
                                        g_ln3, b_ln3, b_out,
                                        (const s16x8*)Wp1, (const s16x8*)Wp2,
                                        (const s16x8*)WpI, (const s16x8*)WpO,
                                        out_dx, out_z);
}

// Round 3
// 366.626 us; speedup vs baseline: 2.7960x; 2.7960x over previous
//
#include <hip/hip_runtime.h>
#include <hip/hip_bf16.h>

typedef float f32x4 __attribute__((ext_vector_type(4)));
typedef short s16x8 __attribute__((ext_vector_type(8)));

__device__ __forceinline__ short f2bf(float f) {
    union { float f; unsigned int u; } c; c.f = f;
    return (short)((c.u + 0x8000u) >> 16);            // round-to-nearest (ties away)
}
__device__ __forceinline__ float bf2f(unsigned int v16) {
    union { unsigned int u; float f; } c; c.u = v16 << 16; return c.f;
}
__device__ __forceinline__ s16x8 cvt8(float4 f0, float4 f1) {
    s16x8 v;
    v[0] = f2bf(f0.x); v[1] = f2bf(f0.y); v[2] = f2bf(f0.z); v[3] = f2bf(f0.w);
    v[4] = f2bf(f1.x); v[5] = f2bf(f1.y); v[6] = f2bf(f1.z); v[7] = f2bf(f1.w);
    return v;
}

// ---------------- weight packing: MFMA B-fragment order ----------------
__global__ void pack_w(const float* __restrict__ W, short* __restrict__ out,
                       int Kreal, int N, int nbTot, int total) {
    int tid = blockIdx.x * 256 + threadIdx.x;
    if (tid >= total) return;
    int j  = tid & 7;
    int l  = (tid >> 3) & 63;
    int blk = tid >> 9;            // ks*nbTot + nb
    int nb = blk % nbTot, ks = blk / nbTot;
    int k = ks * 32 + (l >> 4) * 8 + j;
    int n = nb * 16 + (l & 15);
    out[tid] = (k < Kreal) ? f2bf(W[(long)k * N + n]) : (short)0;
}

// ---------------- wave-local layernorm over 256 cols, 32 rows ----------------
__device__ __forceinline__ void ln_wave2(f32x4 (&acc)[2][16], const float* __restrict__ g,
                                         const float* __restrict__ bl, int r) {
#pragma unroll
    for (int mi = 0; mi < 2; ++mi)
#pragma unroll
        for (int j = 0; j < 4; ++j) {
            float s = 0.f, q = 0.f;
#pragma unroll
            for (int ni = 0; ni < 16; ++ni) { float v = acc[mi][ni][j]; s += v; q += v * v; }
#pragma unroll
            for (int m = 1; m < 16; m <<= 1) { s += __shfl_xor(s, m, 64); q += __shfl_xor(q, m, 64); }
            float mean = s * (1.f / 256.f);
            float var  = fmaxf(q * (1.f / 256.f) - mean * mean, 0.f);
            float rstd = rsqrtf(var + 1e-5f);
#pragma unroll
            for (int ni = 0; ni < 16; ++ni) acc[mi][ni][j] = (acc[mi][ni][j] - mean) * rstd;
        }
#pragma unroll
    for (int ni = 0; ni < 16; ++ni) {
        float gg = g[ni * 16 + r], bb = bl[ni * 16 + r];
#pragma unroll
        for (int mi = 0; mi < 2; ++mi)
#pragma unroll
            for (int j = 0; j < 4; ++j) acc[mi][ni][j] = acc[mi][ni][j] * gg + bb;
    }
}

#define MFMA(a, b, c) __builtin_amdgcn_mfma_f32_16x16x32_bf16((a), (b), (c), 0, 0, 0)

// ---------------- main fused kernel: 1 wave per block, 32 rows per wave ----------------
__global__ __launch_bounds__(64, 2) void deq_main(
    const float* __restrict__ x, const float* __restrict__ z,
    const float* __restrict__ b_inp, const float* __restrict__ g_lni, const float* __restrict__ b_lni,
    const float* __restrict__ b1, const float* __restrict__ g_ln1, const float* __restrict__ b_ln1,
    const float* __restrict__ b2, const float* __restrict__ g_ln2, const float* __restrict__ b_ln2,
    const float* __restrict__ g_ln3, const float* __restrict__ b_ln3,
    const float* __restrict__ b_out,
    const s16x8* __restrict__ Wp1, const s16x8* __restrict__ Wp2,
    const s16x8* __restrict__ WpI, const s16x8* __restrict__ WpO,
    float* __restrict__ out_dx, float* __restrict__ out_z)
{
    __shared__ __align__(16) short T_sh[32 * 256];   // 16 KB wave-local transpose buffer

    const int lane = threadIdx.x & 63;
    const int r = lane & 15, kg = lane >> 4;
    const long r0 = (long)blockIdx.x * 32;
    // swizzle: byte ^= (row&3)<<4 ; A-read base is offset-foldable over ks
    const int tbase = (r * 512 + kg * 16) ^ ((r & 3) << 4);

    f32x4 acc[2][16];

    // ================= GEMM1: z @ W1 (+b1 as C-init) =================
#pragma unroll
    for (int ni = 0; ni < 16; ++ni) {
        float bb = b1[ni * 16 + r];
#pragma unroll
        for (int mi = 0; mi < 2; ++mi) acc[mi][ni] = (f32x4){bb, bb, bb, bb};
    }
    {
        const float* z0 = z + (r0 + r) * 256 + kg * 8;
        const float* z1r = z + (r0 + 16 + r) * 256 + kg * 8;
        s16x8 bA[8], bB[8];
#pragma unroll
        for (int ni = 0; ni < 8; ++ni) bA[ni] = Wp1[ni * 64 + lane];
#pragma unroll
        for (int ni = 0; ni < 8; ++ni) bB[ni] = Wp1[(8 + ni) * 64 + lane];
#pragma unroll
        for (int ks = 0; ks < 8; ++ks) {
            const float4* p0 = (const float4*)(z0 + ks * 32);
            const float4* p1 = (const float4*)(z1r + ks * 32);
            s16x8 a0 = cvt8(p0[0], p0[1]);
            s16x8 a1 = cvt8(p1[0], p1[1]);
#pragma unroll
            for (int ni = 0; ni < 8; ++ni) {
                acc[0][ni] = MFMA(a0, bA[ni], acc[0][ni]);
                acc[1][ni] = MFMA(a1, bA[ni], acc[1][ni]);
            }
            if (ks < 7) {
#pragma unroll
                for (int ni = 0; ni < 8; ++ni) bA[ni] = Wp1[((ks + 1) * 16 + ni) * 64 + lane];
            }
#pragma unroll
            for (int ni = 0; ni < 8; ++ni) {
                acc[0][8 + ni] = MFMA(a0, bB[ni], acc[0][8 + ni]);
                acc[1][8 + ni] = MFMA(a1, bB[ni], acc[1][8 + ni]);
            }
            if (ks < 7) {
#pragma unroll
                for (int ni = 0; ni < 8; ++ni) bB[ni] = Wp1[((ks + 1) * 16 + 8 + ni) * 64 + lane];
            }
        }
    }

    // issue x loads early (HBM latency hides under LN1 + z1 transpose)
    float4 xr[2][4];
    {
        const float* x0 = x + (r0 + r) * 48;
        const float* x1 = x + (r0 + 16 + r) * 48;
        xr[0][0] = ((const float4*)(x0 + kg * 8))[0];
        xr[0][1] = ((const float4*)(x0 + kg * 8))[1];
        xr[1][0] = ((const float4*)(x1 + kg * 8))[0];
        xr[1][1] = ((const float4*)(x1 + kg * 8))[1];
        if (kg < 2) {
            xr[0][2] = ((const float4*)(x0 + 32 + kg * 8))[0];
            xr[0][3] = ((const float4*)(x0 + 32 + kg * 8))[1];
            xr[1][2] = ((const float4*)(x1 + 32 + kg * 8))[0];
            xr[1][3] = ((const float4*)(x1 + 32 + kg * 8))[1];
        } else {
            xr[0][2] = xr[0][3] = xr[1][2] = xr[1][3] = (float4){0.f, 0.f, 0.f, 0.f};
        }
    }

    // relu + LN1 -> z1
#pragma unroll
    for (int mi = 0; mi < 2; ++mi)
#pragma unroll
        for (int ni = 0; ni < 16; ++ni)
#pragma unroll
            for (int j = 0; j < 4; ++j) acc[mi][ni][j] = fmaxf(acc[mi][ni][j], 0.f);
    ln_wave2(acc, g_ln1, b_ln1, r);

    // write z1 (bf16) to LDS, C-layout -> row-major swizzled
#pragma unroll
    for (int mi = 0; mi < 2; ++mi)
#pragma unroll
        for (int j = 0; j < 4; ++j) {
            int row = mi * 16 + kg * 4 + j;
            int rb = row * 512, sw = (row & 3) << 4;
#pragma unroll
            for (int ni = 0; ni < 16; ++ni)
                *(short*)((char*)T_sh + ((rb + (ni * 16 + r) * 2) ^ sw)) = f2bf(acc[mi][ni][j]);
        }

    // ================= x-GEMM: x @ W_inp (+b_inp as C-init) =================
#pragma unroll
    for (int ni = 0; ni < 16; ++ni) {
        float bb = b_inp[ni * 16 + r];
#pragma unroll
        for (int mi = 0; mi < 2; ++mi) acc[mi][ni] = (f32x4){bb, bb, bb, bb};
    }
    {
        s16x8 a00 = cvt8(xr[0][0], xr[0][1]);
        s16x8 a10 = cvt8(xr[1][0], xr[1][1]);
        s16x8 a01 = cvt8(xr[0][2], xr[0][3]);
        s16x8 a11 = cvt8(xr[1][2], xr[1][3]);
#pragma unroll
        for (int ni = 0; ni < 16; ++ni) {
            s16x8 b = WpI[ni * 64 + lane];
            acc[0][ni] = MFMA(a00, b, acc[0][ni]);
            acc[1][ni] = MFMA(a10, b, acc[1][ni]);
        }
#pragma unroll
        for (int ni = 0; ni < 16; ++ni) {
            s16x8 b = WpI[(16 + ni) * 64 + lane];
            acc[0][ni] = MFMA(a01, b, acc[0][ni]);
            acc[1][ni] = MFMA(a11, b, acc[1][ni]);
        }
    }
    ln_wave2(acc, g_lni, b_lni, r);       // acc = xinp

    // + b2 (C-init for GEMM2)
#pragma unroll
    for (int ni = 0; ni < 16; ++ni) {
        float bb = b2[ni * 16 + r];
#pragma unroll
        for (int mi = 0; mi < 2; ++mi)
#pragma unroll
            for (int j = 0; j < 4; ++j) acc[mi][ni][j] += bb;
    }

    // ================= GEMM2: + z1 @ W2 (A from LDS) =================
    {
        s16x8 bA[8], bB[8];
#pragma unroll
        for (int ni = 0; ni < 8; ++ni) bA[ni] = Wp2[ni * 64 + lane];
#pragma unroll
        for (int ni = 0; ni < 8; ++ni) bB[ni] = Wp2[(8 + ni) * 64 + lane];
#pragma unroll
        for (int ks = 0; ks < 8; ++ks) {
            s16x8 a0 = *(const s16x8*)((const char*)T_sh + tbase + ks * 64);
            s16x8 a1 = *(const s16x8*)((const char*)T_sh + tbase + ks * 64 + 8192);
#pragma unroll
            for (int ni = 0; ni < 8; ++ni) {
                acc[0][ni] = MFMA(a0, bA[ni], acc[0][ni]);
                acc[1][ni] = MFMA(a1, bA[ni], acc[1][ni]);
            }
            if (ks < 7) {
#pragma unroll
                for (int ni = 0; ni < 8; ++ni) bA[ni] = Wp2[((ks + 1) * 16 + ni) * 64 + lane];
            }
#pragma unroll
            for (int ni = 0; ni < 8; ++ni) {
                acc[0][8 + ni] = MFMA(a0, bB[ni], acc[0][8 + ni]);
                acc[1][8 + ni] = MFMA(a1, bB[ni], acc[1][8 + ni]);
            }
            if (ks < 7) {
#pragma unroll
                for (int ni = 0; ni < 8; ++ni) bB[ni] = Wp2[((ks + 1) * 16 + 8 + ni) * 64 + lane];
            }
        }
    }
    ln_wave2(acc, g_ln2, b_ln2, r);       // acc = inner

    // ---- z_out = LN3(relu(z1 + inner)) ; z1 reloaded from LDS ----
#pragma unroll
    for (int mi = 0; mi < 2; ++mi)
#pragma unroll
        for (int j = 0; j < 4; ++j) {
            int row = mi * 16 + kg * 4 + j;
            int rb = row * 512, sw = (row & 3) << 4;
#pragma unroll
            for (int ni = 0; ni < 16; ++ni) {
                unsigned short v = *(const unsigned short*)((const char*)T_sh + ((rb + (ni * 16 + r) * 2) ^ sw));
                acc[mi][ni][j] = fmaxf(acc[mi][ni][j] + bf2f(v), 0.f);
            }
        }
    ln_wave2(acc, g_ln3, b_ln3, r);       // acc = z_out

    // write z_out (bf16) to LDS (source for out-GEMM A and the coalesced f32 copy)
#pragma unroll
    for (int mi = 0; mi < 2; ++mi)
#pragma unroll
        for (int j = 0; j < 4; ++j) {
            int row = mi * 16 + kg * 4 + j;
            int rb = row * 512, sw = (row & 3) << 4;
#pragma unroll
            for (int ni = 0; ni < 16; ++ni)
                *(short*)((char*)T_sh + ((rb + (ni * 16 + r) * 2) ^ sw)) = f2bf(acc[mi][ni][j]);
        }

    // ================= out-GEMM: dx = z_out @ W_out (+b_out as C-init) =================
    f32x4 ao[2][2];
#pragma unroll
    for (int ni = 0; ni < 2; ++ni) {
        float bb = b_out[ni * 16 + r];
#pragma unroll
        for (int mi = 0; mi < 2; ++mi) ao[mi][ni] = (f32x4){bb, bb, bb, bb};
    }
#pragma unroll
    for (int ks = 0; ks < 8; ++ks) {
        s16x8 a0 = *(const s16x8*)((const char*)T_sh + tbase + ks * 64);
        s16x8 a1 = *(const s16x8*)((const char*)T_sh + tbase + ks * 64 + 8192);
#pragma unroll
        for (int ni = 0; ni < 2; ++ni) {
            s16x8 b = WpO[(ks * 2 + ni) * 64 + lane];
            ao[0][ni] = MFMA(a0, b, ao[0][ni]);
            ao[1][ni] = MFMA(a1, b, ao[1][ni]);
        }
    }
#pragma unroll
    for (int mi = 0; mi < 2; ++mi)
#pragma unroll
        for (int ni = 0; ni < 2; ++ni)
#pragma unroll
            for (int j = 0; j < 4; ++j)
                out_dx[(r0 + mi * 16 + kg * 4 + j) * 32 + ni * 16 + r] = ao[mi][ni][j];

    // ---- coalesced out_z copy: LDS bf16 -> global f32, 1KB/instr ----
    {
        float* zo = out_z + r0 * 256;
#pragma unroll
        for (int it = 0; it < 16; ++it) {
            int row = it * 2 + (lane >> 5);
            int cb = (lane & 31) * 16;                  // byte offset within row (8 bf16)
            int addr = (row * 512 + cb) ^ ((row & 3) << 4);
            int4 w = *(const int4*)((const char*)T_sh + addr);
            float4 o0, o1;
            o0.x = bf2f((unsigned)w.x & 0xffffu); o0.y = bf2f((unsigned)w.x >> 16);
            o0.z = bf2f((unsigned)w.y & 0xffffu); o0.w = bf2f((unsigned)w.y >> 16);
            o1.x = bf2f((unsigned)w.z & 0xffffu); o1.y = bf2f((unsigned)w.z >> 16);
            o1.z = bf2f((unsigned)w.w & 0xffffu); o1.w = bf2f((unsigned)w.w >> 16);
            int e = row * 256 + (lane & 31) * 8;
            *(float4*)(zo + e) = o0;
            *(float4*)(zo + e + 4) = o1;
        }
    }
}

extern "C" void kernel_launch(void* const* d_in, const int* in_sizes, int n_in,
                              void* d_out, int out_size, void* d_ws, size_t ws_size,
                              hipStream_t stream) {
    const float* x      = (const float*)d_in[0];
    const float* z      = (const float*)d_in[1];
    const float* W_inp  = (const float*)d_in[2];
    const float* b_inp  = (const float*)d_in[3];
    const float* g_lni  = (const float*)d_in[4];
    const float* b_lni  = (const float*)d_in[5];
    const float* W1     = (const float*)d_in[6];
    const float* b1     = (const float*)d_in[7];
    const float* g_ln1  = (const float*)d_in[8];
    const float* b_ln1  = (const float*)d_in[9];
    const float* W2     = (const float*)d_in[10];
    const float* b2     = (const float*)d_in[11];
    const float* g_ln2  = (const float*)d_in[12];
    const float* b_ln2  = (const float*)d_in[13];
    const float* g_ln3  = (const float*)d_in[14];
    const float* b_ln3  = (const float*)d_in[15];
    const float* W_out  = (const float*)d_in[16];
    const float* b_out  = (const float*)d_in[17];

    short* Wp1 = (short*)d_ws;            // 8*16*64*8  = 65536 bf16
    short* Wp2 = Wp1 + 65536;             // 65536
    short* WpI = Wp2 + 65536;             // 2*16*64*8  = 16384
    short* WpO = WpI + 16384;             // 8*2*64*8   = 8192

    pack_w<<<256, 256, 0, stream>>>(W1,    Wp1, 256, 256, 16, 65536);
    pack_w<<<256, 256, 0, stream>>>(W2,    Wp2, 256, 256, 16, 65536);
    pack_w<<< 64, 256, 0, stream>>>(W_inp, WpI,  48, 256, 16, 16384);
    pack_w<<< 32, 256, 0, stream>>>(W_out, WpO, 256,  32,  2,  8192);

    const long B = 262144;
    float* out_dx = (float*)d_out;
    float* out_z  = out_dx + B * 32;
    deq_main<<<B / 32, 64, 0, stream>>>(x, z, b_inp, g_lni, b_lni,
                                        b1, g_ln1, b_ln1, b2, g_ln2, b_ln2,
                                        g_ln3, b_ln3, b_out,
                                        (const s16x8*)Wp1, (const s16x8*)Wp2,
                                        (const s16x8*)WpI, (const s16x8*)WpO,
                                        out_dx, out_z);
}